// Round 6
// baseline (163.416 us; speedup 1.0000x reference)
//
#include <hip/hip_runtime.h>

typedef __attribute__((ext_vector_type(4))) float f32x4;
typedef __attribute__((ext_vector_type(8))) short bf16x8;

__device__ __forceinline__ short f2bf(float f) {
    union { float f; unsigned u; } v; v.f = f;
    unsigned u = v.u + 0x7FFFu + ((v.u >> 16) & 1u);   // RNE
    return (short)(u >> 16);
}
__device__ __forceinline__ int pack_bf2(float a, float b) {
    union { float f; unsigned u; } ua, ub; ua.f = a; ub.f = b;
    unsigned x = ua.u + 0x8000u, y = ub.u + 0x8000u;   // round half-up
    return (int)__builtin_amdgcn_perm(y, x, 0x07060302u);
}

// sum over lanes {l, l^16, l^32, l^48}.
// gfx950 permlane{16,32}_swap: VALU pipe, no DS traffic. Verified on-HW (r3).
#if __has_builtin(__builtin_amdgcn_permlane16_swap) && \
    __has_builtin(__builtin_amdgcn_permlane32_swap)
__device__ __forceinline__ float quad_sum(float dp) {
    unsigned u = __float_as_uint(dp);
    auto r1 = __builtin_amdgcn_permlane16_swap(u, u, false, false);
    float s = __uint_as_float(r1[0]) + __uint_as_float(r1[1]);
    unsigned v = __float_as_uint(s);
    auto r2 = __builtin_amdgcn_permlane32_swap(v, v, false, false);
    return __uint_as_float(r2[0]) + __uint_as_float(r2[1]);
}
#else
__device__ __forceinline__ float quad_sum(float dp) {
    dp += __shfl_xor(dp, 16, 64);
    dp += __shfl_xor(dp, 32, 64);
    return dp;
}
#endif

// ---------------------------------------------------------------------------
// Prep (16 blocks x 256): device Cholesky A = L·L^T (fp32, in-LDS), then
// pack M = L^T (upper-triangular) into the MFMA fragment layout:
//  AbP16: per c, frag f=(rt*2+kc)*64+L holds M_c[pi(rt*16+(L&15))][32kc+8(L>>4)+j]
//         (zero where col < row; frags 4 and 6 are all-zero -> main skips them)
//  biasP: fp32, row-permuted: biasP[c][p] = -(L^T m)[pi(p)]  (C-init term)
// Main then computes z = M·x + C  (= L^T(x-m) rows) and d = sum z^2 — no
// bf16 unpacking dot, no kscal, d >= 0 by construction.
// ---------------------------------------------------------------------------
__global__ void gmm_prep(const float* __restrict__ Ainv,
                         const float* __restrict__ means,
                         short* __restrict__ AbP16,
                         float* __restrict__ biasP) {
    __shared__ float sA[64 * 68];
    __shared__ float sm[64];
    __shared__ float sb[64];
    const int c = blockIdx.x, t = threadIdx.x;
    const int w4 = t >> 6;                 // wave id, for trailing-update split
    const float* A = Ainv + c * 4096;
    #pragma unroll
    for (int i = 0; i < 4; ++i) {
        int flat = i * 1024 + t * 4;
        int r = flat >> 6, col = flat & 63;
        *(f32x4*)&sA[r * 68 + col] = *(const f32x4*)(A + flat);
    }
    if (t < 64) sm[t] = means[c * 64 + t];
    __syncthreads();

    // in-place Cholesky: lower triangle of sA becomes L (diag included)
    for (int k = 0; k < 64; ++k) {
        if (t < 64) {                      // single wave: read-before-write safe
            float Lkk = __builtin_sqrtf(sA[k * 68 + k]);
            float inv = 1.f / Lkk;
            if (t == k)      sA[k * 68 + k] = Lkk;
            else if (t > k)  sA[t * 68 + k] *= inv;
        }
        __syncthreads();
        {   // trailing update, rows j>k, cols k+1..j; 4 waves split cols
            int j = t & 63;
            if (j > k) {
                float ljk = sA[j * 68 + k];
                for (int i = k + 1 + w4; i <= j; i += 4)
                    sA[j * 68 + i] -= ljk * sA[i * 68 + k];
            }
        }
        __syncthreads();
    }

    {   // b[j] = (L^T m)[j] = sum_{k>=j} L[k][j] m[k]   (4 lanes per row)
        int j = t >> 2, seg = t & 3;
        float p = 0.f;
        #pragma unroll
        for (int k2 = 0; k2 < 16; ++k2) {
            int k = seg * 16 + k2;
            float Mv = (k >= j) ? sA[k * 68 + j] : 0.f;
            p += Mv * sm[k];
        }
        p += __shfl_xor(p, 1, 64); p += __shfl_xor(p, 2, 64);
        if (seg == 0) sb[j] = p;
    }
    __syncthreads();
    if (t < 64) {
        int rt = t >> 4, qh = (t >> 2) & 3, r = t & 3;
        int pj = (rt >> 1) * 32 + 8 * qh + 4 * (rt & 1) + r;
        biasP[c * 64 + t] = -sb[pj];
    }
    #pragma unroll
    for (int rep = 0; rep < 2; ++rep) {     // permuted M = L^T fragments
        int f = rep * 256 + t;
        int rt = f >> 7, kc = (f >> 6) & 1, L = f & 63;
        int ln = L & 15, q = L >> 4;
        int pj = (rt >> 1) * 32 + 8 * (ln >> 2) + 4 * (rt & 1) + (ln & 3);
        int kbase = 32 * kc + 8 * q;
        bf16x8 v;
        #pragma unroll
        for (int j = 0; j < 8; ++j) {
            int kk = kbase + j;
            float x = (kk >= pj) ? sA[kk * 68 + pj] : 0.f;   // M[pj][kk]=L[kk][pj]
            v[j] = f2bf(x);
        }
        *(bf16x8*)(AbP16 + c * 4096 + f * 8) = v;
    }
}

union BFrag { bf16x8 v; int i[4]; };

// ---------------------------------------------------------------------------
// Main (1024 blocks x 256): 4 waves x 64 samples; x packed bf16 persistent in
// regs (32 VGPRs). NO LDS, NO barriers: M-fragments read per comp straight
// from global (128 KB total, L2/L3-resident, coalesced dwordx4).
// M upper-triangular: frags (rt=2,3, kc=0) are all-zero -> 24 MFMA and
// 6 af loads per comp instead of 32/8. d = sum z^2 (fp32 acc squares, no
// bf16 unpack). Quad reduction via permlane swaps; coalesced store.
// ---------------------------------------------------------------------------
__global__ __launch_bounds__(256, 4) void gmm_main(
    const float* __restrict__ X,
    const float* __restrict__ weights,
    const short* __restrict__ AbP16,
    const float* __restrict__ biasP,
    float* __restrict__ out) {

    const int tid = threadIdx.x;
    const int lane = tid & 63, w = tid >> 6;
    const int q = lane >> 4, ln = lane & 15;
    const int base = blockIdx.x * 256 + w * 64;

    // x -> persistent packed bf16 B-frags (transient fp32 per tile)
    BFrag xb[4][2];
    #pragma unroll
    for (int t = 0; t < 4; ++t) {
        const float* xr = X + (size_t)(base + t * 16 + ln) * 64 + 8 * q;
        #pragma unroll
        for (int kc = 0; kc < 2; ++kc) {
            f32x4 a = *(const f32x4*)(xr + 32 * kc);
            f32x4 b = *(const f32x4*)(xr + 32 * kc + 4);
            xb[t][kc].i[0] = pack_bf2(a[0], a[1]);
            xb[t][kc].i[1] = pack_bf2(a[2], a[3]);
            xb[t][kc].i[2] = pack_bf2(b[0], b[1]);
            xb[t][kc].i[3] = pack_bf2(b[2], b[3]);
        }
    }

    float slog[4] = {0.f, 0.f, 0.f, 0.f};

    #pragma unroll 1
    for (int c = 0; c < 16; ++c) {
        const short* aP = AbP16 + c * 4096 + lane * 8;
        bf16x8 af0 = *(const bf16x8*)(aP + 0 * 512);   // rt0 kc0
        bf16x8 af1 = *(const bf16x8*)(aP + 1 * 512);   // rt0 kc1
        bf16x8 af2 = *(const bf16x8*)(aP + 2 * 512);   // rt1 kc0
        bf16x8 af3 = *(const bf16x8*)(aP + 3 * 512);   // rt1 kc1
        bf16x8 af5 = *(const bf16x8*)(aP + 5 * 512);   // rt2 kc1 (kc0 zero)
        bf16x8 af7 = *(const bf16x8*)(aP + 7 * 512);   // rt3 kc1 (kc0 zero)
        f32x4 bias[4];
        #pragma unroll
        for (int rt = 0; rt < 4; ++rt)
            bias[rt] = *(const f32x4*)(biasP + c * 64 + rt * 16 + q * 4);
        const float wcc = weights[c];

        #pragma unroll
        for (int t = 0; t < 4; ++t) {
            f32x4 a0 = __builtin_amdgcn_mfma_f32_16x16x32_bf16(af0, xb[t][0].v, bias[0], 0, 0, 0);
            a0 = __builtin_amdgcn_mfma_f32_16x16x32_bf16(af1, xb[t][1].v, a0, 0, 0, 0);
            f32x4 a1 = __builtin_amdgcn_mfma_f32_16x16x32_bf16(af2, xb[t][0].v, bias[1], 0, 0, 0);
            a1 = __builtin_amdgcn_mfma_f32_16x16x32_bf16(af3, xb[t][1].v, a1, 0, 0, 0);
            f32x4 a2 = __builtin_amdgcn_mfma_f32_16x16x32_bf16(af5, xb[t][1].v, bias[2], 0, 0, 0);
            f32x4 a3 = __builtin_amdgcn_mfma_f32_16x16x32_bf16(af7, xb[t][1].v, bias[3], 0, 0, 0);

            float dp0 = a0[0] * a0[0], dp1 = a1[0] * a1[0];
            float dp2 = a2[0] * a2[0], dp3 = a3[0] * a3[0];
            #pragma unroll
            for (int i = 1; i < 4; ++i) {
                dp0 = fmaf(a0[i], a0[i], dp0);
                dp1 = fmaf(a1[i], a1[i], dp1);
                dp2 = fmaf(a2[i], a2[i], dp2);
                dp3 = fmaf(a3[i], a3[i], dp3);
            }
            float dp = quad_sum((dp0 + dp1) + (dp2 + dp3));
            float d = fmaxf(dp, 1e-30f);
            slog[t] = fmaf(wcc, __builtin_amdgcn_logf(d), slog[t]);
        }
    }

    // slog[] identical across each quad after quad_sum: lane (q,ln)
    // writes sample q*16+ln -> one coalesced 64-wide store per wave
    float s0 = (q & 1) ? slog[1] : slog[0];
    float s1 = (q & 1) ? slog[3] : slog[2];
    float sv = (q & 2) ? s1 : s0;
    out[base + lane] = __builtin_amdgcn_exp2f(sv);
}

extern "C" void kernel_launch(void* const* d_in, const int* in_sizes, int n_in,
                              void* d_out, int out_size, void* d_ws, size_t ws_size,
                              hipStream_t stream) {
    const float* X       = (const float*)d_in[0];
    const float* Ainv    = (const float*)d_in[1];
    const float* means   = (const float*)d_in[2];
    const float* weights = (const float*)d_in[3];
    float* out = (float*)d_out;
    const int N = in_sizes[0] / 64;

    short* AbP16 = (short*)d_ws;                       // 131072 B
    float* biasP = (float*)((char*)d_ws + 131072);     // 4096 B

    gmm_prep<<<dim3(16), dim3(256), 0, stream>>>(Ainv, means, AbP16, biasP);
    gmm_main<<<dim3(N / 256), dim3(256), 0, stream>>>(X, weights, AbP16, biasP, out);
}

// Round 7
// 136.699 us; speedup vs baseline: 1.1954x; 1.1954x over previous
//
#include <hip/hip_runtime.h>

typedef __attribute__((ext_vector_type(4))) float f32x4;
typedef __attribute__((ext_vector_type(8))) short bf16x8;

__device__ __forceinline__ short f2bf(float f) {
    union { float f; unsigned u; } v; v.f = f;
    unsigned u = v.u + 0x7FFFu + ((v.u >> 16) & 1u);   // RNE
    return (short)(u >> 16);
}
__device__ __forceinline__ int pack_bf2(float a, float b) {
    union { float f; unsigned u; } ua, ub; ua.f = a; ub.f = b;
    unsigned x = ua.u + 0x8000u, y = ub.u + 0x8000u;   // round half-up
    return (int)__builtin_amdgcn_perm(y, x, 0x07060302u);
}

// sum over lanes {l, l^16, l^32, l^48}.
// gfx950 permlane{16,32}_swap: VALU pipe, no DS traffic. Verified on-HW (r3).
#if __has_builtin(__builtin_amdgcn_permlane16_swap) && \
    __has_builtin(__builtin_amdgcn_permlane32_swap)
__device__ __forceinline__ float quad_sum(float dp) {
    unsigned u = __float_as_uint(dp);
    auto r1 = __builtin_amdgcn_permlane16_swap(u, u, false, false);
    float s = __uint_as_float(r1[0]) + __uint_as_float(r1[1]);
    unsigned v = __float_as_uint(s);
    auto r2 = __builtin_amdgcn_permlane32_swap(v, v, false, false);
    return __uint_as_float(r2[0]) + __uint_as_float(r2[1]);
}
#else
__device__ __forceinline__ float quad_sum(float dp) {
    dp += __shfl_xor(dp, 16, 64);
    dp += __shfl_xor(dp, 32, 64);
    return dp;
}
#endif

// ---------------------------------------------------------------------------
// Prep (16 blocks x 256): BLOCKED Cholesky A = L·L^T (B=8):
//  - panel: wave 0, rows in registers pc[8], 28 shfl+fma per panel, no LDS
//    in the dependence chain (old scalar version: 47us, 128 barriers,
//    serial per-lane RMW chains, 147K bank conflicts)
//  - trailing rank-8 update: all 256 threads, full-square (upper-triangle
//    garbage never read), LDS stride 65 (==1 mod 32 -> conflict-free cols)
//  - 16 barriers total
// Then pack M = L^T into MFMA fragment layout (frags 4,6 all-zero; main
// skips them) and biasP[c][p] = -(L^T m)[pi(p)].
// ---------------------------------------------------------------------------
__global__ void gmm_prep(const float* __restrict__ Ainv,
                         const float* __restrict__ means,
                         short* __restrict__ AbP16,
                         float* __restrict__ biasP) {
    __shared__ float sA[64 * 65];
    __shared__ float sm[64];
    __shared__ float sb[64];
    const int c = blockIdx.x, t = threadIdx.x;
    const float* A = Ainv + c * 4096;
    #pragma unroll
    for (int i = 0; i < 16; ++i) {         // scalar coalesced stage (stride 65)
        int ft = i * 256 + t;
        sA[(ft >> 6) * 65 + (ft & 63)] = A[ft];
    }
    if (t < 64) sm[t] = means[c * 64 + t];
    __syncthreads();

    #pragma unroll 1
    for (int kb = 0; kb < 8; ++kb) {
        const int k0 = kb * 8;
        if (t < 64) {                      // ---- panel: wave 0, registers ----
            const int j = k0 + t;          // row owned by this lane
            const bool act = (j < 64);
            const int jj = act ? j : 63;   // clamped load, never stored
            float pc[8];
            #pragma unroll
            for (int i = 0; i < 8; ++i) pc[i] = sA[jj * 65 + k0 + i];
            #pragma unroll
            for (int kk = 0; kk < 8; ++kk) {
                float diag = __shfl(pc[kk], kk, 64);
                float s = __builtin_sqrtf(diag);
                float inv = 1.f / s;
                if (t == kk)     pc[kk] = s;
                else if (t > kk) pc[kk] *= inv;
                #pragma unroll
                for (int i = kk + 1; i < 8; ++i) {
                    float lik = __shfl(pc[kk], i, 64);  // unconditional shfl
                    if (t > kk) pc[i] = fmaf(-pc[kk], lik, pc[i]);
                }
            }
            if (act) {
                #pragma unroll
                for (int i = 0; i < 8; ++i) sA[j * 65 + k0 + i] = pc[i];
            }
        }
        __syncthreads();
        {   // ---- trailing rank-8 update: all threads, region [k0+8, 64) ----
            const int r0 = k0 + 8;
            const int W = 64 - r0;
            if (W > 0) {
                const int qc = t & 15;     // col quad
                const int jr = t >> 4;     // row within 16-row pass
                if (qc * 4 < W) {
                    const int i0 = r0 + qc * 4;
                    for (int j = r0 + jr; j < 64; j += 16) {
                        float a0 = 0.f, a1 = 0.f, a2 = 0.f, a3 = 0.f;
                        #pragma unroll
                        for (int k = 0; k < 8; ++k) {
                            float ljk = sA[j * 65 + k0 + k];     // broadcast
                            a0 = fmaf(ljk, sA[(i0 + 0) * 65 + k0 + k], a0);
                            a1 = fmaf(ljk, sA[(i0 + 1) * 65 + k0 + k], a1);
                            a2 = fmaf(ljk, sA[(i0 + 2) * 65 + k0 + k], a2);
                            a3 = fmaf(ljk, sA[(i0 + 3) * 65 + k0 + k], a3);
                        }
                        sA[j * 65 + i0 + 0] -= a0;
                        sA[j * 65 + i0 + 1] -= a1;
                        sA[j * 65 + i0 + 2] -= a2;
                        sA[j * 65 + i0 + 3] -= a3;
                    }
                }
            }
        }
        __syncthreads();
    }

    {   // b[j] = (L^T m)[j] = sum_{k>=j} L[k][j] m[k]   (4 lanes per row)
        int j = t >> 2, seg = t & 3;
        float p = 0.f;
        #pragma unroll
        for (int k2 = 0; k2 < 16; ++k2) {
            int k = seg * 16 + k2;
            float Mv = (k >= j) ? sA[k * 65 + j] : 0.f;
            p += Mv * sm[k];
        }
        p += __shfl_xor(p, 1, 64); p += __shfl_xor(p, 2, 64);
        if (seg == 0) sb[j] = p;
    }
    __syncthreads();
    if (t < 64) {
        int rt = t >> 4, qh = (t >> 2) & 3, r = t & 3;
        int pj = (rt >> 1) * 32 + 8 * qh + 4 * (rt & 1) + r;
        biasP[c * 64 + t] = -sb[pj];
    }
    #pragma unroll
    for (int rep = 0; rep < 2; ++rep) {     // permuted M = L^T fragments
        int f = rep * 256 + t;
        int rt = f >> 7, kc = (f >> 6) & 1, L = f & 63;
        int ln = L & 15, q = L >> 4;
        int pj = (rt >> 1) * 32 + 8 * (ln >> 2) + 4 * (rt & 1) + (ln & 3);
        int kbase = 32 * kc + 8 * q;
        bf16x8 v;
        #pragma unroll
        for (int j = 0; j < 8; ++j) {
            int kk = kbase + j;
            float x = (kk >= pj) ? sA[kk * 65 + pj] : 0.f;   // M[pj][kk]=L[kk][pj]
            v[j] = f2bf(x);
        }
        *(bf16x8*)(AbP16 + c * 4096 + f * 8) = v;
    }
}

union BFrag { bf16x8 v; int i[4]; };

// ---------------------------------------------------------------------------
// Main (1024 blocks x 256) — identical to round 6 (isolating the prep fix):
// 4 waves x 64 samples; x packed bf16 persistent in regs. NO LDS, NO
// barriers: M-fragments read per comp straight from global (128 KB,
// L2/L3-resident, coalesced dwordx4). M upper-triangular: frags (rt=2,3,
// kc=0) all-zero -> 24 MFMA + 6 af loads per comp. d = sum z^2.
// Quad reduction via permlane swaps; coalesced store.
// ---------------------------------------------------------------------------
__global__ __launch_bounds__(256, 4) void gmm_main(
    const float* __restrict__ X,
    const float* __restrict__ weights,
    const short* __restrict__ AbP16,
    const float* __restrict__ biasP,
    float* __restrict__ out) {

    const int tid = threadIdx.x;
    const int lane = tid & 63, w = tid >> 6;
    const int q = lane >> 4, ln = lane & 15;
    const int base = blockIdx.x * 256 + w * 64;

    BFrag xb[4][2];
    #pragma unroll
    for (int t = 0; t < 4; ++t) {
        const float* xr = X + (size_t)(base + t * 16 + ln) * 64 + 8 * q;
        #pragma unroll
        for (int kc = 0; kc < 2; ++kc) {
            f32x4 a = *(const f32x4*)(xr + 32 * kc);
            f32x4 b = *(const f32x4*)(xr + 32 * kc + 4);
            xb[t][kc].i[0] = pack_bf2(a[0], a[1]);
            xb[t][kc].i[1] = pack_bf2(a[2], a[3]);
            xb[t][kc].i[2] = pack_bf2(b[0], b[1]);
            xb[t][kc].i[3] = pack_bf2(b[2], b[3]);
        }
    }

    float slog[4] = {0.f, 0.f, 0.f, 0.f};

    #pragma unroll 1
    for (int c = 0; c < 16; ++c) {
        const short* aP = AbP16 + c * 4096 + lane * 8;
        bf16x8 af0 = *(const bf16x8*)(aP + 0 * 512);   // rt0 kc0
        bf16x8 af1 = *(const bf16x8*)(aP + 1 * 512);   // rt0 kc1
        bf16x8 af2 = *(const bf16x8*)(aP + 2 * 512);   // rt1 kc0
        bf16x8 af3 = *(const bf16x8*)(aP + 3 * 512);   // rt1 kc1
        bf16x8 af5 = *(const bf16x8*)(aP + 5 * 512);   // rt2 kc1 (kc0 zero)
        bf16x8 af7 = *(const bf16x8*)(aP + 7 * 512);   // rt3 kc1 (kc0 zero)
        f32x4 bias[4];
        #pragma unroll
        for (int rt = 0; rt < 4; ++rt)
            bias[rt] = *(const f32x4*)(biasP + c * 64 + rt * 16 + q * 4);
        const float wcc = weights[c];

        #pragma unroll
        for (int t = 0; t < 4; ++t) {
            f32x4 a0 = __builtin_amdgcn_mfma_f32_16x16x32_bf16(af0, xb[t][0].v, bias[0], 0, 0, 0);
            a0 = __builtin_amdgcn_mfma_f32_16x16x32_bf16(af1, xb[t][1].v, a0, 0, 0, 0);
            f32x4 a1 = __builtin_amdgcn_mfma_f32_16x16x32_bf16(af2, xb[t][0].v, bias[1], 0, 0, 0);
            a1 = __builtin_amdgcn_mfma_f32_16x16x32_bf16(af3, xb[t][1].v, a1, 0, 0, 0);
            f32x4 a2 = __builtin_amdgcn_mfma_f32_16x16x32_bf16(af5, xb[t][1].v, bias[2], 0, 0, 0);
            f32x4 a3 = __builtin_amdgcn_mfma_f32_16x16x32_bf16(af7, xb[t][1].v, bias[3], 0, 0, 0);

            float dp0 = a0[0] * a0[0], dp1 = a1[0] * a1[0];
            float dp2 = a2[0] * a2[0], dp3 = a3[0] * a3[0];
            #pragma unroll
            for (int i = 1; i < 4; ++i) {
                dp0 = fmaf(a0[i], a0[i], dp0);
                dp1 = fmaf(a1[i], a1[i], dp1);
                dp2 = fmaf(a2[i], a2[i], dp2);
                dp3 = fmaf(a3[i], a3[i], dp3);
            }
            float dp = quad_sum((dp0 + dp1) + (dp2 + dp3));
            float d = fmaxf(dp, 1e-30f);
            slog[t] = fmaf(wcc, __builtin_amdgcn_logf(d), slog[t]);
        }
    }

    float s0 = (q & 1) ? slog[1] : slog[0];
    float s1 = (q & 1) ? slog[3] : slog[2];
    float sv = (q & 2) ? s1 : s0;
    out[base + lane] = __builtin_amdgcn_exp2f(sv);
}

extern "C" void kernel_launch(void* const* d_in, const int* in_sizes, int n_in,
                              void* d_out, int out_size, void* d_ws, size_t ws_size,
                              hipStream_t stream) {
    const float* X       = (const float*)d_in[0];
    const float* Ainv    = (const float*)d_in[1];
    const float* means   = (const float*)d_in[2];
    const float* weights = (const float*)d_in[3];
    float* out = (float*)d_out;
    const int N = in_sizes[0] / 64;

    short* AbP16 = (short*)d_ws;                       // 131072 B
    float* biasP = (float*)((char*)d_ws + 131072);     // 4096 B

    gmm_prep<<<dim3(16), dim3(256), 0, stream>>>(Ainv, means, AbP16, biasP);
    gmm_main<<<dim3(N / 256), dim3(256), 0, stream>>>(X, weights, AbP16, biasP, out);
}